// Round 1
// baseline (1855.267 us; speedup 1.0000x reference)
//
#include <hip/hip_runtime.h>
#include <cstdint>

#define UNITS 512
#define NB 256
#define NT 128
#define ND 512
#define G3 1536

#define SEQ_ELEMS (16777216L)              // 256*128*512
#define STATE_OFF (SEQ_ELEMS)
#define STEP_OFF  (SEQ_ELEMS + 131072L)

#define BGS 16
#define ROWS_PER_BG 16

#define WS_CNT_OFF 128
#define WS_H_OFF   8192
#define H_ELEMS    131072L                 // 256*512

typedef unsigned short u16;
typedef short short8 __attribute__((ext_vector_type(8)));
typedef float f32x4 __attribute__((ext_vector_type(4)));

__device__ __forceinline__ u16 f2b(float f) {
  unsigned int x = __float_as_uint(f);
  unsigned int r = (x + 0x7FFFu + ((x >> 16) & 1u)) >> 16;
  return (u16)r;
}
__device__ __forceinline__ float b2f(u16 u) {
  return __uint_as_float(((unsigned int)u) << 16);
}

template<int MODE>
__device__ __forceinline__ float ldf(const void* p, long idx) {
  if (MODE) return b2f(((const u16*)p)[idx]);
  else      return ((const float*)p)[idx];
}

// ---------------- dtype sniff + counter init ----------------
// fp32 W: low 16 bits are mantissa noise -> bits[14:7] uniform (~15% in band).
// bf16-packed W: low 16 bits are a bf16 of N(0,0.05) -> exponent in [116,124].
__global__ void sniff_init(const void* W, unsigned int* wsu) {
  int l = threadIdx.x;
  unsigned int v = ((const unsigned int*)W)[l];
  unsigned int elo = (v >> 7) & 0xFFu;
  bool inband = (elo > 90u) && (elo < 130u);
  unsigned long long m = __ballot(inband);
  int cnt = __popcll(m);
  if (l == 0) wsu[0] = (cnt >= 32) ? 1u : 0u;
  if (l < BGS) wsu[WS_CNT_OFF / 4 + l * 32] = 0u;   // one 128B line per group
}

// ---------------- h0 = state (to bf16) ----------------
__global__ void h_init(const void* state, void* ws) {
  unsigned int flag = *(const unsigned int*)ws;
  u16* h0 = (u16*)((char*)ws + WS_H_OFF);
  int i = blockIdx.x * blockDim.x + threadIdx.x;
  if (i < (int)H_ELEMS) {
    h0[i] = flag ? ((const u16*)state)[i] : f2b(((const float*)state)[i]);
  }
}

// stage 96 columns (3 gates x 32 units of this ug) of a [512][1536] matrix
// into LDS, transposed to [c][k] bf16 with XOR swizzle (kills 1KB-stride bank conflict)
template<int MODE>
__device__ void stage_cols(const void* M, int ug, u16* lds) {
  int tid = threadIdx.x;
  #pragma unroll 4
  for (int it = 0; it < 384; ++it) {
    int idx = it * 128 + tid;           // 0..49151
    int k = idx / 96;
    int c = idx - k * 96;               // 0..95
    int col = (c >> 5) * UNITS + ug * 32 + (c & 31);
    float v = ldf<MODE>(M, (long)k * G3 + col);
    unsigned int byte = (unsigned int)c * 1024u +
                        ((((unsigned int)k) * 2u) ^ (((unsigned int)(c & 7)) << 4));
    *(u16*)((char*)lds + byte) = f2b(v);
  }
}

__device__ __forceinline__ short8 read_bfrag(const u16* lds, int c, int k) {
  unsigned int byte = (unsigned int)c * 1024u +
                      ((((unsigned int)k) * 2u) ^ (((unsigned int)(c & 7)) << 4));
  return *(const short8*)((const char*)lds + byte);
}

#define MFMA(a, b, c) __builtin_amdgcn_mfma_f32_16x16x32_bf16((a), (b), (c), 0, 0, 0)

template<int MODE>
__global__ __launch_bounds__(128, 1)
void gru_run(const void* __restrict__ xin, const int* __restrict__ dones,
             const int* __restrict__ stepin, const void* __restrict__ W,
             const void* __restrict__ U, const void* __restrict__ bias,
             void* __restrict__ out, void* __restrict__ ws)
{
  unsigned int flag = *(const unsigned int*)ws;
  if (flag != (unsigned int)MODE) return;

  __shared__ u16 wl[96 * 512];   // 96 KB

  const int tid  = threadIdx.x;
  const int w    = tid >> 6;           // wave 0/1
  const int l    = tid & 63;
  const int l15  = l & 15;
  const int ksub = (l >> 4) * 8;
  const int rsub = (l >> 4) * 4;

  const int bg = blockIdx.x & 15;      // same-XCD under round-robin (locality only)
  const int ug = blockIdx.x >> 4;
  const int r0 = bg * ROWS_PER_BG;
  const int j  = ug * 32 + w * 16 + l15;   // unit this lane owns in epilogue

  unsigned int* cntp = (unsigned int*)((char*)ws + WS_CNT_OFF + bg * 128);
  u16* hws = (u16*)((char*)ws + WS_H_OFF);

  // ---- persistent U fragments in registers (48 x short8 = 192 VGPR) ----
  stage_cols<MODE>(U, ug, wl);
  __syncthreads();
  short8 ufz[16], ufrr[16], ufh[16];
  #pragma unroll
  for (int kt = 0; kt < 16; ++kt) {
    int kb = kt * 32 + ksub;
    ufz[kt]  = read_bfrag(wl,       w * 16 + l15, kb);
    ufrr[kt] = read_bfrag(wl, 32 + w * 16 + l15, kb);
    ufh[kt]  = read_bfrag(wl, 64 + w * 16 + l15, kb);
  }
  __syncthreads();
  // ---- W slice stays in LDS for the whole loop ----
  stage_cols<MODE>(W, ug, wl);
  __syncthreads();

  const int c0 = w * 16 + l15, c1 = 32 + w * 16 + l15, c2 = 64 + w * 16 + l15;

  // biases (xm bias b[0], hm bias b[1]); z/r biases fold together
  float bzs = ldf<MODE>(bias, j)        + ldf<MODE>(bias, G3 + j);
  float brs = ldf<MODE>(bias, 512 + j)  + ldf<MODE>(bias, G3 + 512 + j);
  float bxh = ldf<MODE>(bias, 1024 + j);
  float bhh = ldf<MODE>(bias, (long)G3 + 1024 + j);

  // per-lane step counters for rows r0+rsub+0..3 (redundant across lanes, consistent)
  int sarr[4];
  #pragma unroll
  for (int i = 0; i < 4; ++i) sarr[i] = stepin[r0 + rsub + i];

  for (int t = 0; t < NT; ++t) {
    f32x4 az = {0.f,0.f,0.f,0.f}, ar = {0.f,0.f,0.f,0.f};
    f32x4 axh = {0.f,0.f,0.f,0.f}, ahh = {0.f,0.f,0.f,0.f};

    // ---- x@W part: no h dependency -> compute BEFORE the barrier wait ----
    long xbase = ((long)(r0 + l15) * NT + t) * ND + ksub;
    short8 xf[16];
    #pragma unroll
    for (int kt = 0; kt < 16; ++kt) {
      if (MODE) {
        xf[kt] = *(const short8*)((const u16*)xin + xbase + kt * 32);
      } else {
        const float* p = (const float*)xin + xbase + kt * 32;
        f32x4 lo = *(const f32x4*)p;
        f32x4 hi = *(const f32x4*)(p + 4);
        short8 r;
        r[0] = (short)f2b(lo[0]); r[1] = (short)f2b(lo[1]);
        r[2] = (short)f2b(lo[2]); r[3] = (short)f2b(lo[3]);
        r[4] = (short)f2b(hi[0]); r[5] = (short)f2b(hi[1]);
        r[6] = (short)f2b(hi[2]); r[7] = (short)f2b(hi[3]);
        xf[kt] = r;
      }
    }
    #pragma unroll
    for (int kt = 0; kt < 16; ++kt) {
      int kb = kt * 32 + ksub;
      az  = MFMA(xf[kt], read_bfrag(wl, c0, kb), az);
      ar  = MFMA(xf[kt], read_bfrag(wl, c1, kb), ar);
      axh = MFMA(xf[kt], read_bfrag(wl, c2, kb), axh);
    }

    // ---- wait: siblings (same bg) finished step t-1 ----
    if (t > 0) {
      if (tid == 0) {
        unsigned int target = 16u * (unsigned int)t;
        while (__hip_atomic_load(cntp, __ATOMIC_RELAXED, __HIP_MEMORY_SCOPE_AGENT) < target) {}
        __threadfence();   // agent acquire: invalidate L1/L2 stale h lines
      }
      __syncthreads();
    }

    // ---- h@U part ----
    const u16* hb = hws + (t & 1) * H_ELEMS;
    long hbase = (long)(r0 + l15) * UNITS + ksub;
    short8 hf[16];
    #pragma unroll
    for (int kt = 0; kt < 16; ++kt)
      hf[kt] = *(const short8*)(hb + hbase + kt * 32);
    #pragma unroll
    for (int kt = 0; kt < 16; ++kt) {
      az  = MFMA(hf[kt], ufz[kt],  az);
      ar  = MFMA(hf[kt], ufrr[kt], ar);
      ahh = MFMA(hf[kt], ufh[kt],  ahh);
    }

    // ---- gates + reset + outputs ----
    u16* hn = hws + ((t + 1) & 1) * H_ELEMS;
    #pragma unroll
    for (int i = 0; i < 4; ++i) {
      int row = r0 + rsub + i;
      float z  = 1.0f / (1.0f + __expf(-(az[i] + bzs)));
      float rr = 1.0f / (1.0f + __expf(-(ar[i] + brs)));
      float tx = axh[i] + bxh + rr * (ahh[i] + bhh);
      tx = fminf(15.0f, fmaxf(-15.0f, tx));
      float e  = __expf(2.0f * tx);
      float hcand = (e - 1.0f) / (e + 1.0f);
      float hold = b2f(hb[(long)row * UNITS + j]);
      float hnew = z * hold + (1.0f - z) * hcand;

      // sequences emit pre-reset h_new
      long qo = ((long)row * NT + t) * UNITS + j;
      if (MODE) ((u16*)out)[qo] = f2b(hnew);
      else      ((float*)out)[qo] = hnew;

      int sn = sarr[i] + 1;
      int d  = dones[(long)row * NT + t];
      bool reset = (d == 1) || ((sn & 15) == 0);
      float hkeep = reset ? 0.0f : hnew;
      sarr[i] = reset ? 0 : sn;
      hn[(long)row * UNITS + j] = f2b(hkeep);

      if (t == NT - 1) {
        long so = STATE_OFF + (long)row * UNITS + j;
        if (MODE) ((u16*)out)[so] = f2b(hkeep);
        else      ((float*)out)[so] = hkeep;
        if (w == 0 && l15 == 0 && ug == 0) {
          long po = STEP_OFF + row;
          float sv = (float)sarr[i];
          if (MODE) ((u16*)out)[po] = f2b(sv);
          else      ((float*)out)[po] = sv;
        }
      }
    }

    // ---- arrive (release h writes of step t) ----
    if (t < NT - 1) {
      __syncthreads();                       // drains all threads' stores to L2
      if (tid == 0) {
        __threadfence();                     // agent release: writeback L2
        atomicAdd(cntp, 1u);
      }
    }
  }
}

extern "C" void kernel_launch(void* const* d_in, const int* in_sizes, int n_in,
                              void* d_out, int out_size, void* d_ws, size_t ws_size,
                              hipStream_t stream) {
  const void* xin    = d_in[0];
  const int*  dones  = (const int*)d_in[1];
  const void* state  = d_in[2];
  const int*  stepin = (const int*)d_in[3];
  const void* W      = d_in[4];
  const void* U      = d_in[5];
  const void* bias   = d_in[6];

  sniff_init<<<1, 64, 0, stream>>>(W, (unsigned int*)d_ws);
  h_init<<<256, 512, 0, stream>>>(state, d_ws);
  gru_run<0><<<256, 128, 0, stream>>>(xin, dones, stepin, W, U, bias, d_out, d_ws);
  gru_run<1><<<256, 128, 0, stream>>>(xin, dones, stepin, W, U, bias, d_out, d_ws);
}

// Round 4
// 909.054 us; speedup vs baseline: 2.0409x; 2.0409x over previous
//
#include <hip/hip_runtime.h>
#include <cstdint>

#define UNITS 512
#define NB 256
#define NT 128
#define ND 512
#define G3 1536

#define SEQ_ELEMS (16777216L)              // 256*128*512
#define STATE_OFF (SEQ_ELEMS)
#define STEP_OFF  (SEQ_ELEMS + 131072L)

#define BGS 16
#define ROWS_PER_BG 16

#define WS_CNT_OFF 128
#define WS_H_OFF   8192
#define H_ELEMS    131072L                 // 256*512

typedef unsigned short u16;
typedef short short8 __attribute__((ext_vector_type(8)));
typedef float f32x4 __attribute__((ext_vector_type(4)));

__device__ __forceinline__ u16 f2b(float f) {
  unsigned int x = __float_as_uint(f);
  unsigned int r = (x + 0x7FFFu + ((x >> 16) & 1u)) >> 16;
  return (u16)r;
}
__device__ __forceinline__ float b2f(u16 u) {
  return __uint_as_float(((unsigned int)u) << 16);
}

template<int MODE>
__device__ __forceinline__ float ldf(const void* p, long idx) {
  if (MODE) return b2f(((const u16*)p)[idx]);
  else      return ((const float*)p)[idx];
}

// ---- coherent (cross-XCD) h exchange primitives: per-access sc0/sc1 flags,
// ---- no buffer_wbl2/buffer_inv L2 flushes.
__device__ __forceinline__ void store_h_coherent(const u16* p, u16 v) {
  unsigned int vv = v;
  asm volatile("global_store_short %0, %1, off sc0 sc1"
               :: "v"(p), "v"(vv) : "memory");
}

// 16 pipelined 16B coherent loads + single drain; waitcnt INSIDE the asm so
// outputs are architecturally ready at asm end (no hoist hazard).
// NOTE gfx950 modifier order: offset:N BEFORE sc0 sc1.
__device__ __forceinline__ void load_h16_coherent(const u16* p, short8 hf[16]) {
  asm volatile(
    "global_load_dwordx4 %0, %16, off sc0 sc1\n\t"
    "global_load_dwordx4 %1, %16, off offset:64 sc0 sc1\n\t"
    "global_load_dwordx4 %2, %16, off offset:128 sc0 sc1\n\t"
    "global_load_dwordx4 %3, %16, off offset:192 sc0 sc1\n\t"
    "global_load_dwordx4 %4, %16, off offset:256 sc0 sc1\n\t"
    "global_load_dwordx4 %5, %16, off offset:320 sc0 sc1\n\t"
    "global_load_dwordx4 %6, %16, off offset:384 sc0 sc1\n\t"
    "global_load_dwordx4 %7, %16, off offset:448 sc0 sc1\n\t"
    "global_load_dwordx4 %8, %16, off offset:512 sc0 sc1\n\t"
    "global_load_dwordx4 %9, %16, off offset:576 sc0 sc1\n\t"
    "global_load_dwordx4 %10, %16, off offset:640 sc0 sc1\n\t"
    "global_load_dwordx4 %11, %16, off offset:704 sc0 sc1\n\t"
    "global_load_dwordx4 %12, %16, off offset:768 sc0 sc1\n\t"
    "global_load_dwordx4 %13, %16, off offset:832 sc0 sc1\n\t"
    "global_load_dwordx4 %14, %16, off offset:896 sc0 sc1\n\t"
    "global_load_dwordx4 %15, %16, off offset:960 sc0 sc1\n\t"
    "s_waitcnt vmcnt(0)"
    : "=&v"(hf[0]), "=&v"(hf[1]), "=&v"(hf[2]), "=&v"(hf[3]),
      "=&v"(hf[4]), "=&v"(hf[5]), "=&v"(hf[6]), "=&v"(hf[7]),
      "=&v"(hf[8]), "=&v"(hf[9]), "=&v"(hf[10]), "=&v"(hf[11]),
      "=&v"(hf[12]), "=&v"(hf[13]), "=&v"(hf[14]), "=&v"(hf[15])
    : "v"(p)
    : "memory");
}

// ---------------- dtype sniff + counter init ----------------
__global__ void sniff_init(const void* W, unsigned int* wsu) {
  int l = threadIdx.x;
  unsigned int v = ((const unsigned int*)W)[l];
  unsigned int elo = (v >> 7) & 0xFFu;
  bool inband = (elo > 90u) && (elo < 130u);
  unsigned long long m = __ballot(inband);
  int cnt = __popcll(m);
  if (l == 0) wsu[0] = (cnt >= 32) ? 1u : 0u;
  if (l < BGS) wsu[WS_CNT_OFF / 4 + l * 32] = 0u;   // one 128B line per group
}

// ---------------- h0 = state (to bf16) ----------------
__global__ void h_init(const void* state, void* ws) {
  unsigned int flag = *(const unsigned int*)ws;
  u16* h0 = (u16*)((char*)ws + WS_H_OFF);
  int i = blockIdx.x * blockDim.x + threadIdx.x;
  if (i < (int)H_ELEMS) {
    h0[i] = flag ? ((const u16*)state)[i] : f2b(((const float*)state)[i]);
  }
}

// stage 96 columns (3 gates x 32 units of this ug) of a [512][1536] matrix
// into LDS, transposed to [c][k] bf16 with XOR swizzle
template<int MODE>
__device__ void stage_cols(const void* M, int ug, u16* lds) {
  int tid = threadIdx.x;
  #pragma unroll 4
  for (int it = 0; it < 384; ++it) {
    int idx = it * 128 + tid;           // 0..49151
    int k = idx / 96;
    int c = idx - k * 96;               // 0..95
    int col = (c >> 5) * UNITS + ug * 32 + (c & 31);
    float v = ldf<MODE>(M, (long)k * G3 + col);
    unsigned int byte = (unsigned int)c * 1024u +
                        ((((unsigned int)k) * 2u) ^ (((unsigned int)(c & 7)) << 4));
    *(u16*)((char*)lds + byte) = f2b(v);
  }
}

__device__ __forceinline__ short8 read_bfrag(const u16* lds, int c, int k) {
  unsigned int byte = (unsigned int)c * 1024u +
                      ((((unsigned int)k) * 2u) ^ (((unsigned int)(c & 7)) << 4));
  return *(const short8*)((const char*)lds + byte);
}

#define MFMA(a, b, c) __builtin_amdgcn_mfma_f32_16x16x32_bf16((a), (b), (c), 0, 0, 0)

template<int MODE>
__global__ __launch_bounds__(128, 1)
void gru_run(const void* __restrict__ xin, const int* __restrict__ dones,
             const int* __restrict__ stepin, const void* __restrict__ stin,
             const void* __restrict__ W,
             const void* __restrict__ U, const void* __restrict__ bias,
             void* __restrict__ out, void* __restrict__ ws)
{
  unsigned int flag = *(const unsigned int*)ws;
  if (flag != (unsigned int)MODE) return;

  __shared__ u16 wl[96 * 512];   // 96 KB

  const int tid  = threadIdx.x;
  const int w    = tid >> 6;           // wave 0/1
  const int l    = tid & 63;
  const int l15  = l & 15;
  const int ksub = (l >> 4) * 8;
  const int rsub = (l >> 4) * 4;

  const int bg = blockIdx.x & 15;      // same-XCD under round-robin (locality only)
  const int ug = blockIdx.x >> 4;
  const int r0 = bg * ROWS_PER_BG;
  const int j  = ug * 32 + w * 16 + l15;   // unit this lane owns in epilogue

  unsigned int* cntp = (unsigned int*)((char*)ws + WS_CNT_OFF + bg * 128);
  u16* hws = (u16*)((char*)ws + WS_H_OFF);

  // ---- persistent U fragments in registers (48 x short8 = 192 VGPR) ----
  stage_cols<MODE>(U, ug, wl);
  __syncthreads();
  short8 ufz[16], ufrr[16], ufh[16];
  #pragma unroll
  for (int kt = 0; kt < 16; ++kt) {
    int kb = kt * 32 + ksub;
    ufz[kt]  = read_bfrag(wl,       w * 16 + l15, kb);
    ufrr[kt] = read_bfrag(wl, 32 + w * 16 + l15, kb);
    ufh[kt]  = read_bfrag(wl, 64 + w * 16 + l15, kb);
  }
  __syncthreads();
  // ---- W slice stays in LDS for the whole loop ----
  stage_cols<MODE>(W, ug, wl);
  __syncthreads();

  const int c0 = w * 16 + l15, c1 = 32 + w * 16 + l15, c2 = 64 + w * 16 + l15;

  // biases (xm bias b[0], hm bias b[1]); z/r biases fold together
  float bzs = ldf<MODE>(bias, j)        + ldf<MODE>(bias, G3 + j);
  float brs = ldf<MODE>(bias, 512 + j)  + ldf<MODE>(bias, G3 + 512 + j);
  float bxh = ldf<MODE>(bias, 1024 + j);
  float bhh = ldf<MODE>(bias, (long)G3 + 1024 + j);

  // per-lane step counters + own-h registers for rows r0+rsub+0..3
  int sarr[4];
  float hprev[4];
  #pragma unroll
  for (int i = 0; i < 4; ++i) {
    int row = r0 + rsub + i;
    sarr[i]  = stepin[row];
    hprev[i] = ldf<MODE>(stin, (long)row * UNITS + j);
  }

  for (int t = 0; t < NT; ++t) {
    f32x4 az = {0.f,0.f,0.f,0.f}, ar = {0.f,0.f,0.f,0.f};
    f32x4 axh = {0.f,0.f,0.f,0.f}, ahh = {0.f,0.f,0.f,0.f};

    // ---- x@W part: no h dependency -> compute BEFORE the barrier wait ----
    long xbase = ((long)(r0 + l15) * NT + t) * ND + ksub;
    short8 xf[16];
    #pragma unroll
    for (int kt = 0; kt < 16; ++kt) {
      if (MODE) {
        xf[kt] = *(const short8*)((const u16*)xin + xbase + kt * 32);
      } else {
        const float* p = (const float*)xin + xbase + kt * 32;
        f32x4 lo = *(const f32x4*)p;
        f32x4 hi = *(const f32x4*)(p + 4);
        short8 r;
        r[0] = (short)f2b(lo[0]); r[1] = (short)f2b(lo[1]);
        r[2] = (short)f2b(lo[2]); r[3] = (short)f2b(lo[3]);
        r[4] = (short)f2b(hi[0]); r[5] = (short)f2b(hi[1]);
        r[6] = (short)f2b(hi[2]); r[7] = (short)f2b(hi[3]);
        xf[kt] = r;
      }
    }
    #pragma unroll
    for (int kt = 0; kt < 16; ++kt) {
      int kb = kt * 32 + ksub;
      az  = MFMA(xf[kt], read_bfrag(wl, c0, kb), az);
      ar  = MFMA(xf[kt], read_bfrag(wl, c1, kb), ar);
      axh = MFMA(xf[kt], read_bfrag(wl, c2, kb), axh);
    }

    // ---- wait: siblings (same bg) finished step t-1 ----
    if (t > 0) {
      if (tid == 0) {
        unsigned int target = 16u * (unsigned int)t;
        while (__hip_atomic_load(cntp, __ATOMIC_RELAXED, __HIP_MEMORY_SCOPE_AGENT) < target) {}
      }
      __syncthreads();
    }

    // ---- h@U part (coherent loads bypass stale L1/L2) ----
    const u16* hb = hws + (t & 1) * H_ELEMS;
    long hbase = (long)(r0 + l15) * UNITS + ksub;
    short8 hf[16];
    load_h16_coherent(hb + hbase, hf);
    #pragma unroll
    for (int kt = 0; kt < 16; ++kt) {
      az  = MFMA(hf[kt], ufz[kt],  az);
      ar  = MFMA(hf[kt], ufrr[kt], ar);
      ahh = MFMA(hf[kt], ufh[kt],  ahh);
    }

    // ---- gates + reset; write h (coherent) FIRST, seq store deferred ----
    u16* hn = hws + ((t + 1) & 1) * H_ELEMS;
    float hnew_r[4];
    #pragma unroll
    for (int i = 0; i < 4; ++i) {
      int row = r0 + rsub + i;
      float z  = 1.0f / (1.0f + __expf(-(az[i] + bzs)));
      float rr = 1.0f / (1.0f + __expf(-(ar[i] + brs)));
      float tx = axh[i] + bxh + rr * (ahh[i] + bhh);
      tx = fminf(15.0f, fmaxf(-15.0f, tx));
      float e  = __expf(2.0f * tx);
      float hcand = (e - 1.0f) / (e + 1.0f);
      float hnew = z * hprev[i] + (1.0f - z) * hcand;
      hnew_r[i] = hnew;

      int sn = sarr[i] + 1;
      int d  = dones[(long)row * NT + t];
      bool reset = (d == 1) || ((sn & 15) == 0);
      float hkeep = reset ? 0.0f : hnew;
      sarr[i] = reset ? 0 : sn;
      hprev[i] = hkeep;
      store_h_coherent(hn + (long)row * UNITS + j, f2b(hkeep));
    }

    // ---- arrive: drain h stores, then increment (no L2 flush) ----
    if (t < NT - 1) {
      asm volatile("s_waitcnt vmcnt(0)" ::: "memory");
      __syncthreads();
      if (tid == 0) atomicAdd(cntp, 1u);
    }

    // ---- deferred outputs (off the inter-block critical path) ----
    #pragma unroll
    for (int i = 0; i < 4; ++i) {
      int row = r0 + rsub + i;
      long qo = ((long)row * NT + t) * UNITS + j;
      if (MODE) ((u16*)out)[qo] = f2b(hnew_r[i]);
      else      ((float*)out)[qo] = hnew_r[i];

      if (t == NT - 1) {
        long so = STATE_OFF + (long)row * UNITS + j;
        if (MODE) ((u16*)out)[so] = f2b(hprev[i]);
        else      ((float*)out)[so] = hprev[i];
        if (w == 0 && l15 == 0 && ug == 0) {
          long po = STEP_OFF + row;
          float sv = (float)sarr[i];
          if (MODE) ((u16*)out)[po] = f2b(sv);
          else      ((float*)out)[po] = sv;
        }
      }
    }
  }
}

extern "C" void kernel_launch(void* const* d_in, const int* in_sizes, int n_in,
                              void* d_out, int out_size, void* d_ws, size_t ws_size,
                              hipStream_t stream) {
  const void* xin    = d_in[0];
  const int*  dones  = (const int*)d_in[1];
  const void* stin   = d_in[2];
  const int*  stepin = (const int*)d_in[3];
  const void* W      = d_in[4];
  const void* U      = d_in[5];
  const void* bias   = d_in[6];

  sniff_init<<<1, 64, 0, stream>>>(W, (unsigned int*)d_ws);
  h_init<<<256, 512, 0, stream>>>(stin, d_ws);
  gru_run<0><<<256, 128, 0, stream>>>(xin, dones, stepin, stin, W, U, bias, d_out, d_ws);
  gru_run<1><<<256, 128, 0, stream>>>(xin, dones, stepin, stin, W, U, bias, d_out, d_ws);
}

// Round 5
// 725.709 us; speedup vs baseline: 2.5565x; 1.2526x over previous
//
#include <hip/hip_runtime.h>
#include <cstdint>

#define UNITS 512
#define NB 256
#define NT 128
#define ND 512
#define G3 1536

#define SEQ_ELEMS (16777216L)              // 256*128*512
#define STATE_OFF (SEQ_ELEMS)
#define STEP_OFF  (SEQ_ELEMS + 131072L)

#define BGS 16
#define ROWS_PER_BG 16

#define WS_FLAG_OFF 4096                   // 256 flag lines x 64B = 16KB
#define WS_H_OFF    65536
#define H_ELEMS     131072L                // 256*512

typedef unsigned short u16;
typedef short short8 __attribute__((ext_vector_type(8)));
typedef float f32x4 __attribute__((ext_vector_type(4)));

__device__ __forceinline__ u16 f2b(float f) {
  unsigned int x = __float_as_uint(f);
  unsigned int r = (x + 0x7FFFu + ((x >> 16) & 1u)) >> 16;
  return (u16)r;
}
__device__ __forceinline__ float b2f(u16 u) {
  return __uint_as_float(((unsigned int)u) << 16);
}

template<int MODE>
__device__ __forceinline__ float ldf(const void* p, long idx) {
  if (MODE) return b2f(((const u16*)p)[idx]);
  else      return ((const float*)p)[idx];
}

// ---- coherent (cross-XCD) primitives: per-access sc0/sc1, no L2 flushes ----
__device__ __forceinline__ void store_h_coherent(const u16* p, u16 v) {
  unsigned int vv = v;
  asm volatile("global_store_short %0, %1, off sc0 sc1"
               :: "v"(p), "v"(vv) : "memory");
}
__device__ __forceinline__ void store_flag_coherent(const unsigned int* p, unsigned int v) {
  asm volatile("global_store_dword %0, %1, off sc0 sc1"
               :: "v"(p), "v"(v) : "memory");
}
__device__ __forceinline__ unsigned int load_flag_coherent(const unsigned int* p) {
  unsigned int v;
  asm volatile("global_load_dword %0, %1, off sc0 sc1\n\t"
               "s_waitcnt vmcnt(0)"
               : "=v"(v) : "v"(p) : "memory");
  return v;
}

// 16 pipelined 16B coherent loads + single drain (gfx950: offset BEFORE sc flags)
__device__ __forceinline__ void load_h16_coherent(const u16* p, short8 hf[16]) {
  asm volatile(
    "global_load_dwordx4 %0, %16, off sc0 sc1\n\t"
    "global_load_dwordx4 %1, %16, off offset:64 sc0 sc1\n\t"
    "global_load_dwordx4 %2, %16, off offset:128 sc0 sc1\n\t"
    "global_load_dwordx4 %3, %16, off offset:192 sc0 sc1\n\t"
    "global_load_dwordx4 %4, %16, off offset:256 sc0 sc1\n\t"
    "global_load_dwordx4 %5, %16, off offset:320 sc0 sc1\n\t"
    "global_load_dwordx4 %6, %16, off offset:384 sc0 sc1\n\t"
    "global_load_dwordx4 %7, %16, off offset:448 sc0 sc1\n\t"
    "global_load_dwordx4 %8, %16, off offset:512 sc0 sc1\n\t"
    "global_load_dwordx4 %9, %16, off offset:576 sc0 sc1\n\t"
    "global_load_dwordx4 %10, %16, off offset:640 sc0 sc1\n\t"
    "global_load_dwordx4 %11, %16, off offset:704 sc0 sc1\n\t"
    "global_load_dwordx4 %12, %16, off offset:768 sc0 sc1\n\t"
    "global_load_dwordx4 %13, %16, off offset:832 sc0 sc1\n\t"
    "global_load_dwordx4 %14, %16, off offset:896 sc0 sc1\n\t"
    "global_load_dwordx4 %15, %16, off offset:960 sc0 sc1\n\t"
    "s_waitcnt vmcnt(0)"
    : "=&v"(hf[0]), "=&v"(hf[1]), "=&v"(hf[2]), "=&v"(hf[3]),
      "=&v"(hf[4]), "=&v"(hf[5]), "=&v"(hf[6]), "=&v"(hf[7]),
      "=&v"(hf[8]), "=&v"(hf[9]), "=&v"(hf[10]), "=&v"(hf[11]),
      "=&v"(hf[12]), "=&v"(hf[13]), "=&v"(hf[14]), "=&v"(hf[15])
    : "v"(p)
    : "memory");
}

// ---------------- dtype sniff ----------------
__global__ void sniff_init(const void* W, unsigned int* wsu) {
  int l = threadIdx.x;
  unsigned int v = ((const unsigned int*)W)[l];
  unsigned int elo = (v >> 7) & 0xFFu;
  bool inband = (elo > 90u) && (elo < 130u);
  unsigned long long m = __ballot(inband);
  int cnt = __popcll(m);
  if (l == 0) wsu[0] = (cnt >= 32) ? 1u : 0u;
}

// ---------------- h0 = state (to bf16) + zero flag lines ----------------
__global__ void h_init(const void* state, void* ws) {
  unsigned int flag = *(const unsigned int*)ws;
  u16* h0 = (u16*)((char*)ws + WS_H_OFF);
  int i = blockIdx.x * blockDim.x + threadIdx.x;
  if (i < (int)H_ELEMS) {
    h0[i] = flag ? ((const u16*)state)[i] : f2b(((const float*)state)[i]);
  }
  if (i < 4096) {   // 16KB of flag lines
    ((unsigned int*)((char*)ws + WS_FLAG_OFF))[i] = 0u;
  }
}

// stage 96 columns (3 gates x 32 units of this ug) of [512][1536] into LDS,
// transposed to [c][k] bf16 with XOR swizzle. 256 threads.
template<int MODE>
__device__ void stage_cols(const void* M, int ug, u16* lds) {
  int tid = threadIdx.x;
  #pragma unroll 4
  for (int it = 0; it < 192; ++it) {
    int idx = it * 256 + tid;           // 0..49151
    int k = idx / 96;
    int c = idx - k * 96;               // 0..95
    int col = (c >> 5) * UNITS + ug * 32 + (c & 31);
    float v = ldf<MODE>(M, (long)k * G3 + col);
    unsigned int byte = (unsigned int)c * 1024u +
                        ((((unsigned int)k) * 2u) ^ (((unsigned int)(c & 7)) << 4));
    *(u16*)((char*)lds + byte) = f2b(v);
  }
}

__device__ __forceinline__ short8 read_bfrag(const u16* lds, int c, int k) {
  unsigned int byte = (unsigned int)c * 1024u +
                      ((((unsigned int)k) * 2u) ^ (((unsigned int)(c & 7)) << 4));
  return *(const short8*)((const char*)lds + byte);
}

#define MFMA(a, b, c) __builtin_amdgcn_mfma_f32_16x16x32_bf16((a), (b), (c), 0, 0, 0)

template<int MODE>
__global__ __launch_bounds__(256, 1)
void gru_run(const void* __restrict__ xin, const int* __restrict__ dones,
             const int* __restrict__ stepin, const void* __restrict__ stin,
             const void* __restrict__ W,
             const void* __restrict__ U, const void* __restrict__ bias,
             void* __restrict__ out, void* __restrict__ ws)
{
  unsigned int flag = *(const unsigned int*)ws;
  if (flag != (unsigned int)MODE) return;

  __shared__ u16 wl[96 * 512];                 // 96 KB (U during prologue, then W)
  __shared__ float xmbuf[2][2][3][64][4];      // 12 KB x@W partials, dbuf by t&1
  __shared__ unsigned int sv[8];               // 0,1: xdone[p]; 2,3: consumed[p]; 4: harr

  const int tid  = threadIdx.x;
  const int wv   = tid >> 6;           // 0,1 = h-consumer; 2,3 = x-producer
  const int l    = tid & 63;
  const int l15  = l & 15;
  const int ksub = (l >> 4) * 8;
  const int rsub = (l >> 4) * 4;

  const int bg = blockIdx.x & 15;
  const int ug = blockIdx.x >> 4;
  const int r0 = bg * ROWS_PER_BG;

  unsigned int* flags = (unsigned int*)((char*)ws + WS_FLAG_OFF);  // [bg*16+ug]*16 dwords
  u16* hws = (u16*)((char*)ws + WS_H_OFF);

  if (tid < 8) sv[tid] = 0u;

  // ---- prologue: U frags to hwave regs, W slice to LDS ----
  stage_cols<MODE>(U, ug, wl);
  __syncthreads();
  short8 ufz[16], ufrr[16], ufh[16];
  if (wv < 2) {
    #pragma unroll
    for (int kt = 0; kt < 16; ++kt) {
      int kb = kt * 32 + ksub;
      ufz[kt]  = read_bfrag(wl,      wv * 16 + l15, kb);
      ufrr[kt] = read_bfrag(wl, 32 + wv * 16 + l15, kb);
      ufh[kt]  = read_bfrag(wl, 64 + wv * 16 + l15, kb);
    }
  }
  __syncthreads();
  stage_cols<MODE>(W, ug, wl);
  __syncthreads();
  // ============ no __syncthreads below this line ============

  if (wv >= 2) {
    // ================= x-producer waves =================
    const int xw = wv - 2;
    const int c0 = xw * 16 + l15, c1 = 32 + xw * 16 + l15, c2 = 64 + xw * 16 + l15;
    for (int t = 0; t < NT; ++t) {
      const int p = t & 1;
      // x loads + convert: no dependence on handshake -> run before wait
      long xbase = ((long)(r0 + l15) * NT + t) * ND + ksub;
      short8 xf[16];
      #pragma unroll
      for (int kt = 0; kt < 16; ++kt) {
        if (MODE) {
          xf[kt] = *(const short8*)((const u16*)xin + xbase + kt * 32);
        } else {
          const float* q = (const float*)xin + xbase + kt * 32;
          f32x4 lo = *(const f32x4*)q;
          f32x4 hi = *(const f32x4*)(q + 4);
          short8 r;
          r[0] = (short)f2b(lo[0]); r[1] = (short)f2b(lo[1]);
          r[2] = (short)f2b(lo[2]); r[3] = (short)f2b(lo[3]);
          r[4] = (short)f2b(hi[0]); r[5] = (short)f2b(hi[1]);
          r[6] = (short)f2b(hi[2]); r[7] = (short)f2b(hi[3]);
          xf[kt] = r;
        }
      }
      // wait until hwaves consumed the t-2 partials in this parity buffer
      if (t >= 2) {
        unsigned int tgt = 2u * (unsigned int)(t >> 1);
        while (__hip_atomic_load(&sv[2 + p], __ATOMIC_ACQUIRE,
                                 __HIP_MEMORY_SCOPE_WORKGROUP) < tgt) {}
      }
      f32x4 az = {0,0,0,0}, ar = {0,0,0,0}, axh = {0,0,0,0};
      #pragma unroll
      for (int kt = 0; kt < 16; ++kt) {
        int kb = kt * 32 + ksub;
        az  = MFMA(xf[kt], read_bfrag(wl, c0, kb), az);
        ar  = MFMA(xf[kt], read_bfrag(wl, c1, kb), ar);
        axh = MFMA(xf[kt], read_bfrag(wl, c2, kb), axh);
      }
      *(f32x4*)&xmbuf[p][xw][0][l][0] = az;
      *(f32x4*)&xmbuf[p][xw][1][l][0] = ar;
      *(f32x4*)&xmbuf[p][xw][2][l][0] = axh;
      if (l == 0)
        __hip_atomic_fetch_add(&sv[p], 1u, __ATOMIC_RELEASE,
                               __HIP_MEMORY_SCOPE_WORKGROUP);
    }
    return;
  }

  // ================= h-consumer waves =================
  const int w = wv;
  const int j = ug * 32 + w * 16 + l15;

  float bzs = ldf<MODE>(bias, j)        + ldf<MODE>(bias, G3 + j);
  float brs = ldf<MODE>(bias, 512 + j)  + ldf<MODE>(bias, G3 + 512 + j);
  float bxh = ldf<MODE>(bias, 1024 + j);
  float bhh = ldf<MODE>(bias, (long)G3 + 1024 + j);

  int sarr[4];
  float hprev[4];
  #pragma unroll
  for (int i = 0; i < 4; ++i) {
    int row = r0 + rsub + i;
    sarr[i]  = stepin[row];
    hprev[i] = ldf<MODE>(stin, (long)row * UNITS + j);
  }

  for (int t = 0; t < NT; ++t) {
    const int p = t & 1;
    // prefetch dones(t) before the poll
    int d4_[4];
    #pragma unroll
    for (int i = 0; i < 4; ++i) d4_[i] = dones[(long)(r0 + rsub + i) * NT + t];

    // ---- wait: all 16 sibling blocks finished step t-1 (parallel flag poll) ----
    if (t > 0) {
      const unsigned int* myf = flags + (long)(bg * 16 + l15) * 16;
      bool pred;
      do {
        unsigned int fv = (l < 16) ? load_flag_coherent(myf) : (unsigned int)t;
        pred = (fv >= (unsigned int)t);
      } while (!__all(pred));
    }

    // ---- h loads (coherent, pipelined, drained inside asm) ----
    const u16* hb = hws + p * H_ELEMS;
    long hbase = (long)(r0 + l15) * UNITS + ksub;
    short8 hf[16];
    load_h16_coherent(hb + hbase, hf);

    // ---- pick up x@W partials from producer waves ----
    {
      unsigned int tgt = 2u * (unsigned int)((t >> 1) + 1);
      while (__hip_atomic_load(&sv[p], __ATOMIC_ACQUIRE,
                               __HIP_MEMORY_SCOPE_WORKGROUP) < tgt) {}
    }
    f32x4 az  = *(const f32x4*)&xmbuf[p][w][0][l][0];
    f32x4 ar  = *(const f32x4*)&xmbuf[p][w][1][l][0];
    f32x4 axh = *(const f32x4*)&xmbuf[p][w][2][l][0];
    f32x4 ahh = {0,0,0,0};

    #pragma unroll
    for (int kt = 0; kt < 16; ++kt) {
      az  = MFMA(hf[kt], ufz[kt],  az);
      ar  = MFMA(hf[kt], ufrr[kt], ar);
      ahh = MFMA(hf[kt], ufh[kt],  ahh);
    }
    // partials consumed (regs hold them now); release the parity buffer
    if (l == 0)
      __hip_atomic_fetch_add(&sv[2 + p], 1u, __ATOMIC_RELEASE,
                             __HIP_MEMORY_SCOPE_WORKGROUP);

    // ---- gates + reset; coherent h store first ----
    u16* hn = hws + (p ^ 1) * H_ELEMS;
    float hnew_r[4];
    #pragma unroll
    for (int i = 0; i < 4; ++i) {
      int row = r0 + rsub + i;
      float z  = 1.0f / (1.0f + __expf(-(az[i] + bzs)));
      float rr = 1.0f / (1.0f + __expf(-(ar[i] + brs)));
      float tx = axh[i] + bxh + rr * (ahh[i] + bhh);
      tx = fminf(15.0f, fmaxf(-15.0f, tx));
      float e  = __expf(2.0f * tx);
      float hcand = (e - 1.0f) / (e + 1.0f);
      float hnew = z * hprev[i] + (1.0f - z) * hcand;
      hnew_r[i] = hnew;

      int sn = sarr[i] + 1;
      bool reset = (d4_[i] == 1) || ((sn & 15) == 0);
      float hkeep = reset ? 0.0f : hnew;
      sarr[i] = reset ? 0 : sn;
      hprev[i] = hkeep;
      store_h_coherent(hn + (long)row * UNITS + j, f2b(hkeep));
    }

    // ---- arrive: drain own stores; 2nd-draining hwave publishes the flag ----
    if (t < NT - 1) {
      asm volatile("s_waitcnt vmcnt(0)" ::: "memory");
      unsigned int old = 0;
      if (l == 0)
        old = __hip_atomic_fetch_add(&sv[4], 1u, __ATOMIC_ACQ_REL,
                                     __HIP_MEMORY_SCOPE_WORKGROUP);
      if (l == 0 && old == 2u * (unsigned int)t + 1u)
        store_flag_coherent(flags + (long)(bg * 16 + ug) * 16,
                            (unsigned int)t + 1u);
    }

    // ---- deferred outputs (off the inter-block critical path) ----
    #pragma unroll
    for (int i = 0; i < 4; ++i) {
      int row = r0 + rsub + i;
      long qo = ((long)row * NT + t) * UNITS + j;
      if (MODE) ((u16*)out)[qo] = f2b(hnew_r[i]);
      else      ((float*)out)[qo] = hnew_r[i];

      if (t == NT - 1) {
        long so = STATE_OFF + (long)row * UNITS + j;
        if (MODE) ((u16*)out)[so] = f2b(hprev[i]);
        else      ((float*)out)[so] = hprev[i];
        if (w == 0 && l15 == 0 && ug == 0) {
          long po = STEP_OFF + row;
          float sval = (float)sarr[i];
          if (MODE) ((u16*)out)[po] = f2b(sval);
          else      ((float*)out)[po] = sval;
        }
      }
    }
  }
}

extern "C" void kernel_launch(void* const* d_in, const int* in_sizes, int n_in,
                              void* d_out, int out_size, void* d_ws, size_t ws_size,
                              hipStream_t stream) {
  const void* xin    = d_in[0];
  const int*  dones  = (const int*)d_in[1];
  const void* stin   = d_in[2];
  const int*  stepin = (const int*)d_in[3];
  const void* W      = d_in[4];
  const void* U      = d_in[5];
  const void* bias   = d_in[6];

  sniff_init<<<1, 64, 0, stream>>>(W, (unsigned int*)d_ws);
  h_init<<<256, 512, 0, stream>>>(stin, d_ws);
  gru_run<0><<<256, 256, 0, stream>>>(xin, dones, stepin, stin, W, U, bias, d_out, d_ws);
  gru_run<1><<<256, 256, 0, stream>>>(xin, dones, stepin, stin, W, U, bias, d_out, d_ws);
}